// Round 1
// baseline (681.185 us; speedup 1.0000x reference)
//
#include <hip/hip_runtime.h>
#include <math.h>

#define BB   4
#define NN   1024
#define HID  768
#define NH   12
#define DH   64
#define NRELx 64
#define EE   65536
#define NSEG (BB*NN)   /* 4096 */

// ---------------- K1: stacked QKV projection (f32, compute-both, select at write) ----
// C = X @ W_all^T with W_all = [Wq;Wk;Wv;Wq_kb;Wk_kb;Wv_kb]; epilogue selects by node type.
__global__ __launch_bounds__(256)
void proj_kernel(const float* __restrict__ X, const int* __restrict__ ntype,
                 const float* __restrict__ W0, const float* __restrict__ W1,
                 const float* __restrict__ W2, const float* __restrict__ W3,
                 const float* __restrict__ W4, const float* __restrict__ W5,
                 const float* __restrict__ b0, const float* __restrict__ b1,
                 const float* __restrict__ b2, const float* __restrict__ b3,
                 const float* __restrict__ b4, const float* __restrict__ b5,
                 float* __restrict__ Q, float* __restrict__ Ko, float* __restrict__ V)
{
  __shared__ float Als[16][64];
  __shared__ float Bls[16][64];
  const int tid = threadIdx.x;
  const int tx = tid & 15, ty = tid >> 4;
  const int rt = blockIdx.x * 64;
  const int ct = blockIdx.y * 64;
  const int j  = ct / HID;          // which of the 6 matrices
  const int o0 = ct - j * HID;      // col offset inside that matrix

  const float* Wj; const float* bj;
  if      (j==0){Wj=W0;bj=b0;} else if(j==1){Wj=W1;bj=b1;}
  else if (j==2){Wj=W2;bj=b2;} else if(j==3){Wj=W3;bj=b3;}
  else if (j==4){Wj=W4;bj=b4;} else            {Wj=W5;bj=b5;}

  float acc[4][4];
  #pragma unroll
  for (int i=0;i<4;i++)
    #pragma unroll
    for (int jj=0;jj<4;jj++) acc[i][jj]=0.f;

  const int lr = tid >> 2;   // 0..63 tile row
  const int lc = tid & 3;    // float4 group

  for (int kt=0; kt<HID/16; ++kt) {
    const int K0 = kt*16;
    float4 av = *reinterpret_cast<const float4*>(X  + (size_t)(rt+lr)*HID + K0 + lc*4);
    float4 bv = *reinterpret_cast<const float4*>(Wj + (size_t)(o0+lr)*HID + K0 + lc*4);
    Als[lc*4+0][lr]=av.x; Als[lc*4+1][lr]=av.y; Als[lc*4+2][lr]=av.z; Als[lc*4+3][lr]=av.w;
    Bls[lc*4+0][lr]=bv.x; Bls[lc*4+1][lr]=bv.y; Bls[lc*4+2][lr]=bv.z; Bls[lc*4+3][lr]=bv.w;
    __syncthreads();
    #pragma unroll
    for (int kk=0; kk<16; ++kk) {
      float4 a4 = *reinterpret_cast<const float4*>(&Als[kk][ty*4]);
      float4 b4 = *reinterpret_cast<const float4*>(&Bls[kk][tx*4]);
      float a[4]={a4.x,a4.y,a4.z,a4.w}, b[4]={b4.x,b4.y,b4.z,b4.w};
      #pragma unroll
      for (int i=0;i<4;i++)
        #pragma unroll
        for (int jj=0;jj<4;jj++) acc[i][jj] += a[i]*b[jj];
    }
    __syncthreads();
  }

  float* dst = (j==0||j==3) ? Q : ((j==1||j==4) ? Ko : V);
  const bool wantTok = (j<3);
  #pragma unroll
  for (int i=0;i<4;i++) {
    const int r = rt + ty*4 + i;
    const bool isTok = (ntype[r]==0);
    if (isTok==wantTok) {
      #pragma unroll
      for (int jj=0;jj<4;jj++) {
        const int c = o0 + tx*4 + jj;
        dst[(size_t)r*HID + c] = acc[i][jj] + bj[c];
      }
    }
  }
}

// ---------------- K2: per-edge bilinear logits, one wave per edge ----------------
// logits[e,h] = (1/8) * sum_{d,f} Q[eb,eh][h,d] * M[er][d,f] * K[eb,et][h,f]
__global__ __launch_bounds__(256)
void logits_kernel(const float* __restrict__ Q, const float* __restrict__ Kf,
                   const int* __restrict__ ei, const float* __restrict__ relm,
                   float* __restrict__ L)
{
  const int lane = threadIdx.x & 63;          // = f index
  const int e = blockIdx.x*4 + (threadIdx.x >> 6);
  const int eb = ei[e], eh = ei[EE+e], et = ei[2*EE+e], er = ei[3*EE+e];
  const float* qrow = Q  + (size_t)(eb*NN+eh)*HID;
  const float* krow = Kf + (size_t)(eb*NN+et)*HID;
  const float* M    = relm + (size_t)er*DH*DH;

  float q[NH], k[NH], acc[NH];
  #pragma unroll
  for (int h=0;h<NH;h++){ q[h]=qrow[h*64+lane]; k[h]=krow[h*64+lane]; acc[h]=0.f; }

  for (int d=0; d<64; ++d) {
    const float m = M[d*64 + lane];           // coalesced; one M pass per edge (all heads)
    #pragma unroll
    for (int h=0;h<NH;h++) {
      const float qd = __uint_as_float(
          (unsigned)__builtin_amdgcn_readlane((int)__float_as_uint(q[h]), d));
      acc[h] += qd * m;
    }
  }
  #pragma unroll
  for (int h=0;h<NH;h++) {
    float p = acc[h]*k[h];
    #pragma unroll
    for (int off=32; off>0; off>>=1) p += __shfl_xor(p, off, 64);
    if (lane==0) L[(size_t)e*NH + h] = p * 0.125f;
  }
}

// ---------------- K3: counting sort of edges by segment ----------------
__global__ void hist_kernel(const int* __restrict__ ei, int* __restrict__ cnt){
  const int e = blockIdx.x*256 + threadIdx.x;
  atomicAdd(&cnt[ei[e]*NN + ei[EE+e]], 1);
}

__global__ __launch_bounds__(1024)
void scan_kernel(const int* __restrict__ cnt, int* __restrict__ start, int* __restrict__ cursor){
  __shared__ int sums[1024];
  const int t = threadIdx.x;
  const int c0=cnt[t*4], c1=cnt[t*4+1], c2=cnt[t*4+2], c3=cnt[t*4+3];
  const int s = c0+c1+c2+c3;
  sums[t]=s; __syncthreads();
  for (int off=1; off<1024; off<<=1){
    const int v = (t>=off) ? sums[t-off] : 0;
    __syncthreads();
    sums[t]+=v;
    __syncthreads();
  }
  const int excl = sums[t]-s;
  const int o0=excl, o1=o0+c0, o2=o1+c1, o3=o2+c2;
  start[t*4]=o0;  start[t*4+1]=o1;  start[t*4+2]=o2;  start[t*4+3]=o3;
  cursor[t*4]=o0; cursor[t*4+1]=o1; cursor[t*4+2]=o2; cursor[t*4+3]=o3;
}

__global__ void scatter_kernel(const int* __restrict__ ei, int* __restrict__ cursor,
                               int* __restrict__ order){
  const int e = blockIdx.x*256 + threadIdx.x;
  const int seg = ei[e]*NN + ei[EE+e];
  const int pos = atomicAdd(&cursor[seg], 1);
  order[pos] = e;
}

// ---------------- K4: per-segment softmax + weighted V scatter-sum ----------------
__global__ __launch_bounds__(256)
void segout_kernel(const int* __restrict__ ei, const float* __restrict__ V,
                   const float* __restrict__ emb, const float* __restrict__ L,
                   const int* __restrict__ start, const int* __restrict__ cnt,
                   const int* __restrict__ order, float* __restrict__ out)
{
  const int s = blockIdx.x, tid = threadIdx.x;
  float* o = out + (size_t)s*HID;
  const int n = cnt[s];
  if (n==0){ o[tid]=0.f; o[tid+256]=0.f; o[tid+512]=0.f; return; }

  __shared__ float denom[NH];
  __shared__ float inv[NH];
  if (tid<NH) denom[tid]=0.f;
  __syncthreads();
  const int st = start[s];
  for (int i=tid; i<n*NH; i+=256){
    const int e = order[st + i/NH];
    const int h = i - (i/NH)*NH;
    atomicAdd(&denom[h], expf(L[(size_t)e*NH+h]));   // logits bounded; max-shift not needed
  }
  __syncthreads();
  if (tid<NH) inv[tid] = 1.f/denom[tid];
  __syncthreads();

  const int eb = s >> 10;          // s / NN
  const int h0 = tid >> 6;         // head of column tid
  const float i0=inv[h0], i1=inv[h0+4], i2=inv[h0+8];
  float a0=0.f, a1=0.f, a2=0.f;
  for (int i=0;i<n;i++){
    const int e  = order[st+i];
    const int et = ei[2*EE+e], er = ei[3*EE+e];
    const float* vr   = V   + (size_t)(eb*NN+et)*HID;
    const float* erow = emb + (size_t)er*HID;
    const float p0 = expf(L[(size_t)e*NH+h0  ])*i0;
    const float p1 = expf(L[(size_t)e*NH+h0+4])*i1;
    const float p2 = expf(L[(size_t)e*NH+h0+8])*i2;
    a0 += p0*(vr[tid    ]+erow[tid    ]);
    a1 += p1*(vr[tid+256]+erow[tid+256]);
    a2 += p2*(vr[tid+512]+erow[tid+512]);
  }
  o[tid]=a0; o[tid+256]=a1; o[tid+512]=a2;
}

// ---------------- launcher ----------------
extern "C" void kernel_launch(void* const* d_in, const int* in_sizes, int n_in,
                              void* d_out, int out_size, void* d_ws, size_t ws_size,
                              hipStream_t stream)
{
  const float* X  = (const float*)d_in[0];
  const int*   ei = (const int*)d_in[1];
  const int*   nt = (const int*)d_in[2];
  const float* W[6]; const float* bia[6];
  for (int j=0;j<6;j++){ W[j]=(const float*)d_in[3+2*j]; bia[j]=(const float*)d_in[4+2*j]; }
  const float* relm = (const float*)d_in[15];
  const float* emb  = (const float*)d_in[16];
  float* out = (float*)d_out;

  char* p = (char*)d_ws;
  float* Q  = (float*)p; p += (size_t)NSEG*HID*4;
  float* Kf = (float*)p; p += (size_t)NSEG*HID*4;
  float* V  = (float*)p; p += (size_t)NSEG*HID*4;
  float* L  = (float*)p; p += (size_t)EE*NH*4;
  int* cnt    = (int*)p; p += NSEG*4;
  int* start  = (int*)p; p += NSEG*4;
  int* cursor = (int*)p; p += NSEG*4;
  int* order  = (int*)p; p += (size_t)EE*4;

  hipMemsetAsync(cnt, 0, NSEG*sizeof(int), stream);

  proj_kernel<<<dim3(64,72), 256, 0, stream>>>(X, nt,
      W[0],W[1],W[2],W[3],W[4],W[5],
      bia[0],bia[1],bia[2],bia[3],bia[4],bia[5], Q, Kf, V);
  logits_kernel<<<EE/4, 256, 0, stream>>>(Q, Kf, ei, relm, L);
  hist_kernel<<<EE/256, 256, 0, stream>>>(ei, cnt);
  scan_kernel<<<1, 1024, 0, stream>>>(cnt, start, cursor);
  scatter_kernel<<<EE/256, 256, 0, stream>>>(ei, cursor, order);
  segout_kernel<<<NSEG, 256, 0, stream>>>(ei, V, emb, L, start, cnt, order, out);
}

// Round 2
// 356.251 us; speedup vs baseline: 1.9121x; 1.9121x over previous
//
#include <hip/hip_runtime.h>
#include <math.h>
#include <stdint.h>

#define BB   4
#define NN   1024
#define HID  768
#define NH   12
#define DH   64
#define EE   65536
#define NSEG (BB*NN)   /* 4096 */
#define NOUT 4608      /* 6*HID stacked output features */

typedef __bf16 bf16;
typedef __bf16 bf16x8 __attribute__((ext_vector_type(8)));
typedef float  f32x4  __attribute__((ext_vector_type(4)));

// async global->LDS, 16B per lane (dest must be wave-uniform base + lane*16)
__device__ __forceinline__ void load_lds16(const void* g, void* l) {
  __builtin_amdgcn_global_load_lds(
      (__attribute__((address_space(1))) void*)(uintptr_t)g,
      (__attribute__((address_space(3))) void*)(uintptr_t)l, 16, 0, 0);
}

// LDS XOR swizzle (involution, moves 16B slots within each 128B window)
__device__ __forceinline__ int swz(int byte_off) {
  return byte_off ^ (((byte_off >> 7) & 7) << 4);
}

// ---------------- K0a: convert X to bf16 ----------------
__global__ __launch_bounds__(256)
void convx_kernel(const float* __restrict__ X, bf16* __restrict__ Xb) {
  const int i = (blockIdx.x * 256 + threadIdx.x) * 4;
  float4 v = *reinterpret_cast<const float4*>(X + i);
  bf16 o[4] = {(bf16)v.x, (bf16)v.y, (bf16)v.z, (bf16)v.w};
  *reinterpret_cast<uint64_t*>(Xb + i) = *reinterpret_cast<uint64_t*>(o);
}

// ---------------- K0b: stack+convert weights, concat biases ----------------
__global__ __launch_bounds__(256)
void convw_kernel(const float* __restrict__ W0, const float* __restrict__ W1,
                  const float* __restrict__ W2, const float* __restrict__ W3,
                  const float* __restrict__ W4, const float* __restrict__ W5,
                  const float* __restrict__ b0, const float* __restrict__ b1,
                  const float* __restrict__ b2, const float* __restrict__ b3,
                  const float* __restrict__ b4, const float* __restrict__ b5,
                  bf16* __restrict__ Wb, float* __restrict__ biasAll) {
  const int r = blockIdx.x;          // 0..4607 output feature
  const int j = r / HID;
  const int o = r - j * HID;
  const float* Wj; const float* bj;
  if      (j==0){Wj=W0;bj=b0;} else if(j==1){Wj=W1;bj=b1;}
  else if (j==2){Wj=W2;bj=b2;} else if(j==3){Wj=W3;bj=b3;}
  else if (j==4){Wj=W4;bj=b4;} else            {Wj=W5;bj=b5;}
  const float* src = Wj + (size_t)o * HID;
  bf16* dst = Wb + (size_t)r * HID;
  for (int c = threadIdx.x; c < HID; c += 256) dst[c] = (bf16)src[c];
  if (threadIdx.x == 0) biasAll[r] = bj[o];
}

// ---------------- K1: bf16 MFMA GEMM, C[4096,4608] = Xb @ Wb^T ----------------
// 128x128 tile, 4 waves of 64x64, BK=32, global_load_lds + swizzled LDS.
#define BM 128
#define BN 128
#define BK 32

__global__ __launch_bounds__(256)
void gemm_kernel(const bf16* __restrict__ A, const bf16* __restrict__ Bw,
                 const float* __restrict__ biasAll, const int* __restrict__ ntype,
                 float* __restrict__ Q, float* __restrict__ Ko, float* __restrict__ V)
{
  __shared__ bf16 As[BM * BK];   // 8 KB
  __shared__ bf16 Bs[BN * BK];   // 8 KB
  const int tid  = threadIdx.x;
  const int lane = tid & 63;
  const int w    = tid >> 6;
  const int wrow = w >> 1, wcol = w & 1;
  const int rt = blockIdx.x * BM;       // node-row tile base
  const int ct = blockIdx.y * BN;       // stacked-col tile base (0..4607)

  f32x4 acc[4][4];
  #pragma unroll
  for (int mi=0;mi<4;mi++)
    #pragma unroll
    for (int ni=0;ni<4;ni++) acc[mi][ni] = (f32x4){0.f,0.f,0.f,0.f};

  const char* Ab = (const char*)A;
  const char* Bb = (const char*)Bw;
  char* Asb = (char*)As;
  char* Bsb = (char*)Bs;

  for (int kt = 0; kt < HID / BK; ++kt) {
    // stage: 2 issues x 256 threads x 16B = 8KB per matrix
    #pragma unroll
    for (int i = 0; i < 2; ++i) {
      const int e = i * 256 + tid;      // 16B slot index (0..511)
      const int P = e * 16;             // physical (linear) LDS byte
      const int L = swz(P);             // logical byte it must hold
      const int row = L >> 6;           // logical tile row
      const int inrow = L & 63;         // byte within 64B row
      load_lds16(Ab + ((size_t)(rt + row) * HID + kt * BK) * 2 + inrow, Asb + P);
      load_lds16(Bb + ((size_t)(ct + row) * HID + kt * BK) * 2 + inrow, Bsb + P);
    }
    __syncthreads();   // compiler drains vmcnt(0) before s_barrier

    bf16x8 af[4], bf[4];
    #pragma unroll
    for (int mi = 0; mi < 4; ++mi) {
      const int r = wrow * 64 + mi * 16 + (lane & 15);
      const int L = r * 64 + (lane >> 4) * 16;
      af[mi] = *reinterpret_cast<const bf16x8*>(Asb + swz(L));
    }
    #pragma unroll
    for (int ni = 0; ni < 4; ++ni) {
      const int r = wcol * 64 + ni * 16 + (lane & 15);
      const int L = r * 64 + (lane >> 4) * 16;
      bf[ni] = *reinterpret_cast<const bf16x8*>(Bsb + swz(L));
    }
    #pragma unroll
    for (int mi = 0; mi < 4; ++mi)
      #pragma unroll
      for (int ni = 0; ni < 4; ++ni)
        acc[mi][ni] = __builtin_amdgcn_mfma_f32_16x16x32_bf16(af[mi], bf[ni], acc[mi][ni], 0, 0, 0);
    __syncthreads();
  }

  // epilogue: select tok/kb by row type, add bias, write to Q/K/V
  const int j  = ct / HID;              // which of the 6 matrices (tile never straddles)
  const int o0 = ct - j * HID;
  float* dst = (j==0||j==3) ? Q : ((j==1||j==4) ? Ko : V);
  const bool wantTok = (j < 3);
  #pragma unroll
  for (int mi = 0; mi < 4; ++mi) {
    #pragma unroll
    for (int i = 0; i < 4; ++i) {
      const int r = rt + wrow * 64 + mi * 16 + (lane >> 4) * 4 + i;
      if ((ntype[r] == 0) == wantTok) {
        #pragma unroll
        for (int ni = 0; ni < 4; ++ni) {
          const int cg = wcol * 64 + ni * 16 + (lane & 15);
          dst[(size_t)r * HID + o0 + cg] = acc[mi][ni][i] + biasAll[ct + cg];
        }
      }
    }
  }
}

// ---------------- K2: per-edge bilinear logits, one wave per edge ----------------
__global__ __launch_bounds__(256)
void logits_kernel(const float* __restrict__ Q, const float* __restrict__ Kf,
                   const int* __restrict__ ei, const float* __restrict__ relm,
                   float* __restrict__ L)
{
  const int lane = threadIdx.x & 63;          // = f index
  const int e = blockIdx.x*4 + (threadIdx.x >> 6);
  const int eb = ei[e], eh = ei[EE+e], et = ei[2*EE+e], er = ei[3*EE+e];
  const float* qrow = Q  + (size_t)(eb*NN+eh)*HID;
  const float* krow = Kf + (size_t)(eb*NN+et)*HID;
  const float* M    = relm + (size_t)er*DH*DH;

  float q[NH], k[NH], acc[NH];
  #pragma unroll
  for (int h=0;h<NH;h++){ q[h]=qrow[h*64+lane]; k[h]=krow[h*64+lane]; acc[h]=0.f; }

  for (int d=0; d<64; ++d) {
    const float m = M[d*64 + lane];           // coalesced; one M pass per edge (all heads)
    #pragma unroll
    for (int h=0;h<NH;h++) {
      const float qd = __uint_as_float(
          (unsigned)__builtin_amdgcn_readlane((int)__float_as_uint(q[h]), d));
      acc[h] += qd * m;
    }
  }
  #pragma unroll
  for (int h=0;h<NH;h++) {
    float p = acc[h]*k[h];
    #pragma unroll
    for (int off=32; off>0; off>>=1) p += __shfl_xor(p, off, 64);
    if (lane==0) L[(size_t)e*NH + h] = p * 0.125f;
  }
}

// ---------------- K3: counting sort of edges by segment ----------------
__global__ void hist_kernel(const int* __restrict__ ei, int* __restrict__ cnt){
  const int e = blockIdx.x*256 + threadIdx.x;
  atomicAdd(&cnt[ei[e]*NN + ei[EE+e]], 1);
}

__global__ __launch_bounds__(1024)
void scan_kernel(const int* __restrict__ cnt, int* __restrict__ start, int* __restrict__ cursor){
  __shared__ int sums[1024];
  const int t = threadIdx.x;
  const int c0=cnt[t*4], c1=cnt[t*4+1], c2=cnt[t*4+2], c3=cnt[t*4+3];
  const int s = c0+c1+c2+c3;
  sums[t]=s; __syncthreads();
  for (int off=1; off<1024; off<<=1){
    const int v = (t>=off) ? sums[t-off] : 0;
    __syncthreads();
    sums[t]+=v;
    __syncthreads();
  }
  const int excl = sums[t]-s;
  const int o0=excl, o1=o0+c0, o2=o1+c1, o3=o2+c2;
  start[t*4]=o0;  start[t*4+1]=o1;  start[t*4+2]=o2;  start[t*4+3]=o3;
  cursor[t*4]=o0; cursor[t*4+1]=o1; cursor[t*4+2]=o2; cursor[t*4+3]=o3;
}

__global__ void scatter_kernel(const int* __restrict__ ei, int* __restrict__ cursor,
                               int* __restrict__ order){
  const int e = blockIdx.x*256 + threadIdx.x;
  const int seg = ei[e]*NN + ei[EE+e];
  const int pos = atomicAdd(&cursor[seg], 1);
  order[pos] = e;
}

// ---------------- K4: per-segment softmax + weighted V scatter-sum ----------------
__global__ __launch_bounds__(256)
void segout_kernel(const int* __restrict__ ei, const float* __restrict__ V,
                   const float* __restrict__ emb, const float* __restrict__ L,
                   const int* __restrict__ start, const int* __restrict__ cnt,
                   const int* __restrict__ order, float* __restrict__ out)
{
  const int s = blockIdx.x, tid = threadIdx.x;
  float* o = out + (size_t)s*HID;
  const int n = cnt[s];
  if (n==0){ o[tid]=0.f; o[tid+256]=0.f; o[tid+512]=0.f; return; }

  __shared__ float denom[NH];
  __shared__ float inv[NH];
  if (tid<NH) denom[tid]=0.f;
  __syncthreads();
  const int st = start[s];
  for (int i=tid; i<n*NH; i+=256){
    const int e = order[st + i/NH];
    const int h = i - (i/NH)*NH;
    atomicAdd(&denom[h], expf(L[(size_t)e*NH+h]));   // logits bounded; max-shift not needed
  }
  __syncthreads();
  if (tid<NH) inv[tid] = 1.f/denom[tid];
  __syncthreads();

  const int eb = s >> 10;          // s / NN
  const int h0 = tid >> 6;         // head of column tid
  const float i0=inv[h0], i1=inv[h0+4], i2=inv[h0+8];
  float a0=0.f, a1=0.f, a2=0.f;
  for (int i=0;i<n;i++){
    const int e  = order[st+i];
    const int et = ei[2*EE+e], er = ei[3*EE+e];
    const float* vr   = V   + (size_t)(eb*NN+et)*HID;
    const float* erow = emb + (size_t)er*HID;
    const float p0 = expf(L[(size_t)e*NH+h0  ])*i0;
    const float p1 = expf(L[(size_t)e*NH+h0+4])*i1;
    const float p2 = expf(L[(size_t)e*NH+h0+8])*i2;
    a0 += p0*(vr[tid    ]+erow[tid    ]);
    a1 += p1*(vr[tid+256]+erow[tid+256]);
    a2 += p2*(vr[tid+512]+erow[tid+512]);
  }
  o[tid]=a0; o[tid+256]=a1; o[tid+512]=a2;
}

// ---------------- launcher ----------------
extern "C" void kernel_launch(void* const* d_in, const int* in_sizes, int n_in,
                              void* d_out, int out_size, void* d_ws, size_t ws_size,
                              hipStream_t stream)
{
  const float* X  = (const float*)d_in[0];
  const int*   ei = (const int*)d_in[1];
  const int*   nt = (const int*)d_in[2];
  const float* W[6]; const float* bia[6];
  for (int j=0;j<6;j++){ W[j]=(const float*)d_in[3+2*j]; bia[j]=(const float*)d_in[4+2*j]; }
  const float* relm = (const float*)d_in[15];
  const float* emb  = (const float*)d_in[16];
  float* out = (float*)d_out;

  char* p = (char*)d_ws;
  float* Q  = (float*)p; p += (size_t)NSEG*HID*4;
  float* Kf = (float*)p; p += (size_t)NSEG*HID*4;
  float* V  = (float*)p; p += (size_t)NSEG*HID*4;
  float* L  = (float*)p; p += (size_t)EE*NH*4;
  int* cnt    = (int*)p; p += NSEG*4;
  int* start  = (int*)p; p += NSEG*4;
  int* cursor = (int*)p; p += NSEG*4;
  int* order  = (int*)p; p += (size_t)EE*4;
  bf16* Xb = (bf16*)p;  p += (size_t)NSEG*HID*2;
  bf16* Wb = (bf16*)p;  p += (size_t)NOUT*HID*2;
  float* biasAll = (float*)p; p += NOUT*4;

  hipMemsetAsync(cnt, 0, NSEG*sizeof(int), stream);

  convx_kernel<<<NSEG*HID/4/256, 256, 0, stream>>>(X, Xb);
  convw_kernel<<<NOUT, 256, 0, stream>>>(W[0],W[1],W[2],W[3],W[4],W[5],
      bia[0],bia[1],bia[2],bia[3],bia[4],bia[5], Wb, biasAll);
  gemm_kernel<<<dim3(NSEG/BM, NOUT/BN), 256, 0, stream>>>(Xb, Wb, biasAll, nt, Q, Kf, V);

  logits_kernel<<<EE/4, 256, 0, stream>>>(Q, Kf, ei, relm, L);
  hist_kernel<<<EE/256, 256, 0, stream>>>(ei, cnt);
  scan_kernel<<<1, 1024, 0, stream>>>(cnt, start, cursor);
  scatter_kernel<<<EE/256, 256, 0, stream>>>(ei, cursor, order);
  segout_kernel<<<NSEG, 256, 0, stream>>>(ei, V, emb, L, start, cnt, order, out);
}